// Round 9
// baseline (65.730 us; speedup 1.0000x reference)
//
#include <hip/hip_runtime.h>

// DWT db4, 3 levels, symmetric extension, + linear resize to T=2048, stack 4 coeffs.
// x: [B=16, T=2048, N=512, 1] f32   -> out: [B, N, T, 4] f32
//
// R9: THREE-role wave specialization so the HBM write stream never idles.
// 256 persistent blocks (1/CU), 640 threads:
//   waves 0-3: conv  — wave w owns row w; 3 levels via in-place cA ladder in
//              ib[cur] (R6-verified), cD1/cD2/cD3/cA3 -> coeff[cur] dbuf.
//              Boundary outputs computed into REGS before the interior loop,
//              written after (no read/write-order hazard).
//   waves 4-7: store — resize coeff[prev] and NT-store tile j-1 while conv
//              works tile j. vmcnt-full stalls pace them; write queue stays full.
//   waves 8-9: load  — stage tile j+1 global->reg->LDS (private vmcnt).
// ONE lgkm-only barrier per step (never drains vmcnt).
// LDS: ib[2][4][2056] + coeff[2][4][2088] = 132,608 B dynamic (1 block/CU).

#define TPB      640
#define NT       8            // tiles per block
#define ROWS     4
#define TLEN     2048
#define NCH      512
#define IBSTRIDE 2056         // %32==8
#define CSTRIDE  2088         // %32==8
// coeff row layout: cD1@0(1027), cD2@1032(517), cD3@1552(262), cA3@1816(262)
#define CD1o 0
#define CD2o 1032
#define CD3o 1552
#define CA3o 1816
#define IB_FLOATS  (2 * ROWS * IBSTRIDE)
#define LDS_BYTES  ((IB_FLOATS + 2 * ROWS * CSTRIDE) * 4)

typedef float f32x4 __attribute__((ext_vector_type(4)));

// forward filters (boundary/sym path)
__constant__ float LO[8] = {-0.010597401784997278f,  0.032883011666982945f,  0.030841381835986965f,
                            -0.18703481171888114f,  -0.02798376941698385f,   0.6308807679295904f,
                             0.7148465705525415f,    0.23037781330885523f};
__constant__ float HI[8] = {-0.23037781330885523f,   0.7148465705525415f,   -0.6308807679295904f,
                            -0.02798376941698385f,   0.18703481171888114f,   0.030841381835986965f,
                            -0.032883011666982945f, -0.010597401784997278f};
// reversed filters (interior reads in[2j-6 .. 2j+1] ascending)
__constant__ float RLO[8] = { 0.23037781330885523f,   0.7148465705525415f,   0.6308807679295904f,
                             -0.02798376941698385f,  -0.18703481171888114f,  0.030841381835986965f,
                              0.032883011666982945f, -0.010597401784997278f};
__constant__ float RHI[8] = {-0.010597401784997278f, -0.032883011666982945f, 0.030841381835986965f,
                              0.18703481171888114f,  -0.02798376941698385f,  -0.6308807679295904f,
                              0.7148465705525415f,   -0.23037781330885523f};

// lgkm-only barrier: never drains vmcnt (NT stores / loader prefetch stay in flight)
__device__ __forceinline__ void bar_lgkm() {
    asm volatile("s_waitcnt lgkmcnt(0)" ::: "memory");
    __builtin_amdgcn_s_barrier();
}

__device__ __forceinline__ int sym_idx(int e, int S) {
    int m = e - 6;
    m = (m < 0) ? (-1 - m) : m;
    m = (m >= S) ? (2 * S - 1 - m) : m;
    return m;
}

// One wave computes one full level for its own row. lo may alias in (in-place
// ladder): within-iteration reads precede writes; iteration i+1 reads from
// index >=128i+122 > writes of iter i (<=64i+63); boundary handled via regs.
__device__ __forceinline__ void wave_level(const float* in, int S,
                                           float* lo, float* hi, int lane) {
    const int O    = (S + 7) >> 1;
    const int jmax = (S - 2) >> 1;
    const int NB   = O - (jmax - 2);    // 6 or 7

    // boundary outputs into regs FIRST (reads original in[])
    float blo = 0.0f, bhi = 0.0f;
    int bj = 0;
    if (lane < NB) {
        bj = (lane < 3) ? lane : (jmax + lane - 2);
        const int e0 = 2 * bj + 7;
        #pragma unroll
        for (int k = 0; k < 8; ++k) {
            const float v = in[sym_idx(e0 - k, S)];
            blo = fmaf(LO[k], v, blo);
            bhi = fmaf(HI[k], v, bhi);
        }
    }
    // interior (j in [3, jmax])
    for (int j = 3 + lane; j <= jmax; j += 64) {
        const float* p = in + 2 * j - 6;     // 8B-aligned
        float v[8];
        *(float2*)&v[0] = ((const float2*)p)[0];
        *(float2*)&v[2] = ((const float2*)p)[1];
        *(float2*)&v[4] = ((const float2*)p)[2];
        *(float2*)&v[6] = ((const float2*)p)[3];
        float slo = 0.0f, shi = 0.0f;
        #pragma unroll
        for (int k = 0; k < 8; ++k) {
            slo = fmaf(RLO[k], v[k], slo);
            shi = fmaf(RHI[k], v[k], shi);
        }
        lo[j] = slo;
        hi[j] = shi;
    }
    // boundary writes LAST
    if (lane < NB) { lo[bj] = blo; hi[bj] = bhi; }
}

__device__ __forceinline__ void lerp_coef(int S, int t, int& i0, int& i1, float& w) {
    const float scale = (float)S * (1.0f / 2048.0f);   // exact fp32 for S in {262,517,1027}
    float p = ((float)t + 0.5f) * scale - 0.5f;
    p = fminf(fmaxf(p, 0.0f), (float)(S - 1));
    i0 = (int)p;
    i1 = min(i0 + 1, S - 1);
    w = p - (float)i0;
}

__device__ __forceinline__ float mix2(float a, float b, float w) {
    return a * (1.0f - w) + b * w;
}

// XCD x=p&7 owns tiles [x*256,(x+1)*256); 32 co-XCD blocks take 32 consecutive
// tiles per step (input 128B lines shared in L2 within the step).
__device__ __forceinline__ int tile_row0(int p, int j) {
    const int tile = (p & 7) * 256 + (p >> 3) + 32 * j;
    return tile * ROWS;
}

__device__ __forceinline__ void load_tile(const float* __restrict__ x, int p, int j,
                                          int lt, float4* pre) {
    const int row0 = tile_row0(p, j);
    const float4* s = (const float4*)(x + (size_t)(row0 >> 9) * TLEN * NCH + (row0 & 511));
    #pragma unroll
    for (int i = 0; i < 16; ++i) pre[i] = s[(lt + i * 128) * (NCH / 4)];
}

__device__ __forceinline__ void write_tile(float* ibase, int par, int lt, const float4* pre) {
    float* b = ibase + par * ROWS * IBSTRIDE;
    #pragma unroll
    for (int i = 0; i < 16; ++i) {
        const int t = lt + i * 128;
        b[0 * IBSTRIDE + t] = pre[i].x;
        b[1 * IBSTRIDE + t] = pre[i].y;
        b[2 * IBSTRIDE + t] = pre[i].z;
        b[3 * IBSTRIDE + t] = pre[i].w;
    }
}

__global__ __launch_bounds__(TPB)
void dwt_kernel(const float* __restrict__ x, float* __restrict__ out) {
    extern __shared__ float smem[];
    float* ibase = smem;                  // [2][ROWS][IBSTRIDE]
    float* cbase = smem + IB_FLOATS;      // [2][ROWS][CSTRIDE]
    const int tid  = threadIdx.x;
    const int wid  = tid >> 6;
    const int lane = tid & 63;
    const int p    = blockIdx.x;

    if (wid >= 8) {
        // ---------------- loader: 2 waves ----------------
        const int lt = tid - 512;
        float4 pre[16];
        load_tile(x, p, 0, lt, pre);
        write_tile(ibase, 0, lt, pre);    // waits OUR vmcnt only
        bar_lgkm();
        for (int j = 0; j <= NT; ++j) {
            if (j + 1 < NT) {
                load_tile(x, p, j + 1, lt, pre);
                write_tile(ibase, (j + 1) & 1, lt, pre);
            }
            bar_lgkm();
        }
    } else if (wid < 4) {
        // ---------------- conv: 4 waves, one row each ----------------
        bar_lgkm();
        for (int j = 0; j <= NT; ++j) {
            if (j < NT) {
                float* a = ibase + ((j & 1) * ROWS + wid) * IBSTRIDE;
                float* c = cbase + ((j & 1) * ROWS + wid) * CSTRIDE;
                wave_level(a, 2048, a,        c + CD1o, lane);  // a0 -> cA1(ip), cD1
                wave_level(a, 1027, a,        c + CD2o, lane);  // cA1 -> cA2(ip), cD2
                wave_level(a,  517, c + CA3o, c + CD3o, lane);  // cA2 -> cA3, cD3 (to coeff)
            }
            bar_lgkm();
        }
    } else {
        // ---------------- storer: 4 waves, one row each ----------------
        const int r = wid - 4;
        bar_lgkm();
        for (int j = 0; j <= NT; ++j) {
            if (j >= 1) {
                const float* c = cbase + (((j - 1) & 1) * ROWS + r) * CSTRIDE;
                const int row0 = tile_row0(p, j - 1);
                f32x4* dst = (f32x4*)out + (size_t)(row0 + r) * TLEN;
                for (int i = 0; i < TLEN / 64; ++i) {
                    const int t = lane + (i << 6);
                    int i0a, i1a; float wa; lerp_coef( 262, t, i0a, i1a, wa);  // cA3 & cD3
                    int i0b, i1b; float wb; lerp_coef( 517, t, i0b, i1b, wb);  // cD2
                    int i0c, i1c; float wc; lerp_coef(1027, t, i0c, i1c, wc);  // cD1
                    f32x4 o;
                    o.x = mix2(c[CA3o + i0a], c[CA3o + i1a], wa);
                    o.y = mix2(c[CD3o + i0a], c[CD3o + i1a], wa);
                    o.z = mix2(c[CD2o + i0b], c[CD2o + i1b], wb);
                    o.w = mix2(c[CD1o + i0c], c[CD1o + i1c], wc);
                    __builtin_nontemporal_store(o, &dst[t]);
                }
            }
            bar_lgkm();
        }
    }
}

extern "C" void kernel_launch(void* const* d_in, const int* in_sizes, int n_in,
                              void* d_out, int out_size, void* d_ws, size_t ws_size,
                              hipStream_t stream) {
    const float* x = (const float*)d_in[0];
    float* out = (float*)d_out;
    hipFuncSetAttribute((const void*)dwt_kernel,
                        hipFuncAttributeMaxDynamicSharedMemorySize, LDS_BYTES);
    hipLaunchKernelGGL(dwt_kernel, dim3(256), dim3(TPB), LDS_BYTES, stream, x, out);
}